// Round 12
// baseline (150.586 us; speedup 1.0000x reference)
//
#include <hip/hip_runtime.h>
#include <hip/hip_bf16.h>

typedef __attribute__((ext_vector_type(4))) float f32x4;
typedef __attribute__((ext_vector_type(8))) short s16x8;
typedef __attribute__((ext_vector_type(4))) short s16x4;

#define BB 2
#define NN 2048
#define HH 1024
#define NHEAD 16
#define HDIM 64

__device__ __forceinline__ short f2bf(float f) {
  union { float f; unsigned u; } v; v.f = f;
  unsigned r = v.u + 0x7fffu + ((v.u >> 16) & 1u);
  return (short)(r >> 16);
}

__device__ __forceinline__ f32x4 zf4() { f32x4 z; z[0]=0.f; z[1]=0.f; z[2]=0.f; z[3]=0.f; return z; }

__device__ __forceinline__ f32x4 mfma16(s16x8 a, s16x8 b, f32x4 c) {
  return __builtin_amdgcn_mfma_f32_16x16x32_bf16(a, b, c, 0, 0, 0);
}

__device__ __forceinline__ s16x4 cvt4(f32x4 v) {
  s16x4 o; o[0]=f2bf(v[0]); o[1]=f2bf(v[1]); o[2]=f2bf(v[2]); o[3]=f2bf(v[3]); return o;
}

__device__ __forceinline__ float vexp2(float x) {
  float r; asm("v_exp_f32 %0, %1" : "=v"(r) : "v"(x)); return r;
}

__device__ __forceinline__ float vrcp(float x) {
  float r; asm("v_rcp_f32 %0, %1" : "=v"(r) : "v"(x)); return r;
}

__device__ __forceinline__ float vmax3(float a, float b, float c) {
  float r; asm("v_max3_f32 %0, %1, %2, %3" : "=v"(r) : "v"(a), "v"(b), "v"(c)); return r;
}

__device__ __forceinline__ unsigned cvtpk_bf16(float lo, float hi) {
  unsigned r; asm("v_cvt_pk_bf16_f32 %0, %1, %2" : "=v"(r) : "v"(lo), "v"(hi)); return r;
}

// async global->LDS, 16B per lane; lds ptr must be wave-uniform base (HW adds lane*16)
__device__ __forceinline__ void gload_lds16(const short* g, short* l) {
  __builtin_amdgcn_global_load_lds(
      (const __attribute__((address_space(1))) unsigned*)g,
      (__attribute__((address_space(3))) unsigned*)l, 16, 0, 0);
}

// ---------------- prep: fp32->bf16 conversions + rope tables + mask bias ----------------
__global__ __launch_bounds__(256) void prep_kernel(
    const float* __restrict__ feat, const int* __restrict__ mask,
    const float* __restrict__ wq, const float* __restrict__ wk,
    const float* __restrict__ wv, const float* __restrict__ wo,
    short* __restrict__ fbf, short* __restrict__ wqb, short* __restrict__ wkb,
    short* __restrict__ wvb, short* __restrict__ wob,
    float* __restrict__ cosb, float* __restrict__ sinb,
    float* __restrict__ mbias, int* __restrict__ mseg) {
  const int tid = blockIdx.x * blockDim.x + threadIdx.x;
  const int nth = gridDim.x * blockDim.x;
  const int NF4 = BB*NN*HH/4;
  for (int i = tid; i < NF4; i += nth)
    ((s16x4*)fbf)[i] = cvt4(((const f32x4*)feat)[i]);
  const int NW4 = HH*HH/4;
  for (int i = tid; i < NW4; i += nth) {
    ((s16x4*)wqb)[i] = cvt4(((const f32x4*)wq)[i]);
    ((s16x4*)wkb)[i] = cvt4(((const f32x4*)wk)[i]);
    ((s16x4*)wvb)[i] = cvt4(((const f32x4*)wv)[i]);
    ((s16x4*)wob)[i] = cvt4(((const f32x4*)wo)[i]);
  }
  // rope table: cos/sin[pos][f], f in [0,32), inv_freq = 10000^(-f/32)
  for (int i = tid; i < NN*32; i += nth) {
    int pos = i >> 5, f = i & 31;
    float inv = __expf(-(float)f * 0.28782313662425572f);  // ln(10000)/32
    float ang = (float)pos * inv;
    float s, c;
    sincosf(ang, &s, &c);
    cosb[i] = c; sinb[i] = s;
  }
  // mask bias: 0 if valid, -1e30 if masked (finite so s-m never cancels to 0)
  for (int i = tid; i < BB*NN; i += nth)
    mbias[i] = mask[i] ? 0.f : -1.0e30f;
  // per-64-key segment flag: 1 if ANY key in segment is masked
  for (int i = tid; i < BB*(NN/64); i += nth) {
    int bb = i / (NN/64), sg = i % (NN/64);
    int any = 0;
    for (int j = 0; j < 64; ++j) any |= (mask[bb*NN + sg*64 + j] == 0);
    mseg[i] = any;
  }
}

// ---------------- GEMM core 128x128 (outproj): BK=32, waves 2x2, per-wave 64x64 ----------------
__device__ __forceinline__ void gemm128_core(
    const short* __restrict__ A, const short* __restrict__ W,
    int bm, int bn, short* smem, f32x4 acc[4][4]) {
  const int tid = threadIdx.x;
  const int lane = tid & 63, wid = tid >> 6;
  const int wr = wid >> 1, wc = wid & 1;
  const int g = lane >> 4, lr = lane & 15;
#pragma unroll
  for (int i = 0; i < 4; ++i)
#pragma unroll
    for (int j = 0; j < 4; ++j) acc[i][j] = zf4();

  const int srow = wid*16 + (lane >> 2);
  const int scol = (lane & 3) * 8;
  const short* Abase = A + (size_t)(bm*128 + srow)*HH + scol;
  const short* Wbase = W + (size_t)(bn*128 + srow)*HH + scol;

  auto stage = [&](int b, int t) {
    const short* ga = Abase + t*32;
    const short* gb = Wbase + t*32;
    short* la = smem + b*8192 + wid*512;          // wave-uniform LDS base
    short* lb = smem + b*8192 + 4096 + wid*512;
    gload_lds16(ga,          la);
    gload_lds16(ga + 64*HH,  la + 2048);
    gload_lds16(gb,          lb);
    gload_lds16(gb + 64*HH,  lb + 2048);
  };

  stage(0, 0);
  asm volatile("s_waitcnt vmcnt(0)");
  __syncthreads();

  const int NT = HH / 32;
  int cur = 0;
  for (int t = 0; t < NT; ++t) {
    if (t + 1 < NT) stage(cur ^ 1, t + 1);  // async loads overlap MFMA below
    const short* At = smem + cur*8192;
    const short* Bt = At + 4096;
    s16x8 af[4], bf[4];
#pragma unroll
    for (int mf = 0; mf < 4; ++mf)
      af[mf] = *(const s16x8*)&At[(wr*64 + mf*16 + lr)*32 + g*8];
#pragma unroll
    for (int nf = 0; nf < 4; ++nf)
      bf[nf] = *(const s16x8*)&Bt[(wc*64 + nf*16 + lr)*32 + g*8];
#pragma unroll
    for (int mf = 0; mf < 4; ++mf)
#pragma unroll
      for (int nf = 0; nf < 4; ++nf)
        acc[mf][nf] = mfma16(af[mf], bf[nf], acc[mf][nf]);
    __syncthreads();  // barrier drain completes the staged loads for next iter
    cur ^= 1;
  }
}

// ---------------- GEMM core 256x128 (qkv): BK=32, waves 2x2, per-wave 128x64 ----------------
// 12 ds_read_b128 per 32 MFMA (vs 8:16 at 128^2) -> 1.33x FLOP per LDS byte.
// LDS: buf b: A[256][32] at b*12288, B[128][32] at b*12288+8192 (48KB dbuf total)
__device__ __forceinline__ void gemm256_core(
    const short* __restrict__ A, const short* __restrict__ W,
    int bm, int bn, short* smem, f32x4 acc[8][4]) {
  const int tid = threadIdx.x;
  const int lane = tid & 63, wid = tid >> 6;
  const int wr = wid >> 1, wc = wid & 1;
  const int g = lane >> 4, lr = lane & 15;
#pragma unroll
  for (int i = 0; i < 8; ++i)
#pragma unroll
    for (int j = 0; j < 4; ++j) acc[i][j] = zf4();

  const int srow = wid*16 + (lane >> 2);   // 0..63 within a 64-row slab
  const int scol = (lane & 3) * 8;
  const short* Abase = A + (size_t)(bm*256 + srow)*HH + scol;
  const short* Wbase = W + (size_t)(bn*128 + srow)*HH + scol;

  auto stage = [&](int b, int t) {
    const short* ga = Abase + t*32;
    const short* gb = Wbase + t*32;
    short* la = smem + b*12288 + wid*512;          // wave-uniform LDS base
    short* lb = smem + b*12288 + 8192 + wid*512;
    gload_lds16(ga,           la);
    gload_lds16(ga + 64*HH,   la + 2048);
    gload_lds16(ga + 128*HH,  la + 4096);
    gload_lds16(ga + 192*HH,  la + 6144);
    gload_lds16(gb,           lb);
    gload_lds16(gb + 64*HH,   lb + 2048);
  };

  stage(0, 0);
  asm volatile("s_waitcnt vmcnt(0)");
  __syncthreads();

  const int NT = HH / 32;
  int cur = 0;
  for (int t = 0; t < NT; ++t) {
    if (t + 1 < NT) stage(cur ^ 1, t + 1);
    const short* At = smem + cur*12288;
    const short* Bt = At + 8192;
    s16x8 af[8], bf[4];
#pragma unroll
    for (int mf = 0; mf < 8; ++mf)
      af[mf] = *(const s16x8*)&At[(wr*128 + mf*16 + lr)*32 + g*8];
#pragma unroll
    for (int nf = 0; nf < 4; ++nf)
      bf[nf] = *(const s16x8*)&Bt[(wc*64 + nf*16 + lr)*32 + g*8];
#pragma unroll
    for (int mf = 0; mf < 8; ++mf)
#pragma unroll
      for (int nf = 0; nf < 4; ++nf)
        acc[mf][nf] = mfma16(af[mf], bf[nf], acc[mf][nf]);
    __syncthreads();
    cur ^= 1;
  }
}

// ---------------- QKV projection + RoPE + layout (256x128 tile) ----------------
// z=0: Q (rope, *0.125*log2e) -> [b,h,n,d] ; z=1: K (rope) -> [b,h,n,d] ; z=2: V -> V^T [b,h,d,n]
__global__ __launch_bounds__(256) void qkv_kernel(
    const short* __restrict__ fbf, const short* __restrict__ wqb,
    const short* __restrict__ wkb, const short* __restrict__ wvb,
    const float* __restrict__ cosb, const float* __restrict__ sinb,
    short* __restrict__ qb, short* __restrict__ kb, short* __restrict__ vtb) {
  __shared__ short smem[24576];   // 48KB: gemm dbuf; reused as transpose scratch
  const int bm = blockIdx.y, bn = blockIdx.x, z = blockIdx.z;
  const short* W = (z == 0) ? wqb : ((z == 1) ? wkb : wvb);
  f32x4 acc[8][4];
  gemm256_core(fbf, W, bm, bn, smem, acc);

  const int tid = threadIdx.x, lane = tid & 63, wid = tid >> 6;
  const int wr = wid >> 1, wc = wid & 1, g = lane >> 4, lr = lane & 15;
  const int head = bn*2 + wc;
  const int m0 = bm*256 + wr*128;   // 128-row band; never straddles batch boundary
  const int b = m0 / NN;

  if (z < 2) {
    short* dst = (z == 0) ? qb : kb;
    // Q: fold 1/sqrt(d) AND log2(e) (we use exp2 in attention)
    const float scale = (z == 0) ? 0.18033688011112042f : 1.0f;
#pragma unroll
    for (int mf = 0; mf < 8; ++mf) {
#pragma unroll
      for (int r = 0; r < 4; ++r) {
        int m = m0 + mf*16 + g*4 + r;
        int n = m & (NN - 1);
        float c0 = cosb[n*32 + lr],      s0 = sinb[n*32 + lr];
        float c1 = cosb[n*32 + 16 + lr], s1 = sinb[n*32 + 16 + lr];
        float v0 = acc[mf][0][r], v1 = acc[mf][1][r];
        float v2 = acc[mf][2][r], v3 = acc[mf][3][r];
        float o0 = (v0*c0 - v2*s0) * scale;
        float o1 = (v1*c1 - v3*s1) * scale;
        float o2 = (v2*c0 + v0*s0) * scale;
        float o3 = (v3*c1 + v1*s1) * scale;
        size_t base = ((size_t)(b*NHEAD + head)*NN + n)*HDIM;
        dst[base +  0 + lr] = f2bf(o0);
        dst[base + 16 + lr] = f2bf(o1);
        dst[base + 32 + lr] = f2bf(o2);
        dst[base + 48 + lr] = f2bf(o3);
      }
    }
  } else {
    // V: per-wave 128x64 output = two stacked 64x64 tiles; transpose each via
    // per-wave LDS scratch (wave-local ordering -> no barriers between subtiles)
    __syncthreads();   // all waves done with gemm smem
    short* tp = smem + wid*4608;  // [64][72] per wave
    size_t vbase = ((size_t)(b*NHEAD + head)*HDIM)*NN;
#pragma unroll
    for (int s = 0; s < 2; ++s) {
#pragma unroll
      for (int mf = 0; mf < 4; ++mf)
#pragma unroll
        for (int nf = 0; nf < 4; ++nf)
#pragma unroll
          for (int r = 0; r < 4; ++r)
            tp[(nf*16 + lr)*72 + mf*16 + g*4 + r] = f2bf(acc[s*4 + mf][nf][r]);
      const int nbase = (m0 + s*64) & (NN - 1);
#pragma unroll
      for (int it = 0; it < 8; ++it) {
        int j  = it*8 + (lane >> 3);
        int ns = (lane & 7)*8;
        s16x8 vv = *(const s16x8*)&tp[j*72 + ns];
        *(s16x8*)&vtb[vbase + (size_t)j*NN + nbase + ns] = vv;
      }
    }
  }
}

// ---------------- fused flash attention (round-10 verified: 61.2us) ----------------
// QBLK=128, 32 q/wave (2 q-groups), XCD-pinned swizzle, permuted K staging (P in regs),
// ones-MFMA lsum, vcc-only defer-max, K/V LDS dbuf with early writes, 1 barrier/step.
__global__ __launch_bounds__(256) void attn_kernel(
    const short* __restrict__ qb, const short* __restrict__ kb,
    const short* __restrict__ vtb, const float* __restrict__ mbias,
    const int* __restrict__ mseg,
    short* __restrict__ attnb) {
  __shared__ short Kt[2][64*72];   // [buf][perm key][64 d + pad]
  __shared__ short Vt[2][64*72];   // [buf][64 d][64 keys + pad]
  const int tid = threadIdx.x, lane = tid & 63, wid = tid >> 6;
  const int g = lane >> 4, lr = lane & 15;
  const int w = blockIdx.x;
  const int bh = (w & 7)*4 + ((w >> 3) & 3);
  const int qt = w >> 5;
  const int b = bh >> 4;
  const int q0 = qt*128 + wid*32;

  const short* qpA = qb + ((size_t)bh*NN + q0 + lr)*HDIM + g*8;
  s16x8 qfA0 = *(const s16x8*)(qpA);
  s16x8 qfA1 = *(const s16x8*)(qpA + 32);
  const short* qpB = qpA + 16*HDIM;
  s16x8 qfB0 = *(const s16x8*)(qpB);
  s16x8 qfB1 = *(const s16x8*)(qpB + 32);

  s16x8 one8;
#pragma unroll
  for (int i = 0; i < 8; ++i) one8[i] = (short)0x3F80;  // bf16 1.0

  f32x4 accA[4], accB[4];
#pragma unroll
  for (int i = 0; i < 4; ++i) { accA[i] = zf4(); accB[i] = zf4(); }
  f32x4 acclA = zf4(), acclB = zf4();
  float mrunA = -3.0e38f, mrunB = -3.0e38f;

  const int* msp = mseg + b*(NN/64);
  int segflag = (lane < 32) ? msp[lane] : 0;
  unsigned segbits = (unsigned)__ballot(segflag != 0);

  const int sr = tid >> 2;
  const int sc = (tid & 3) * 16;
  const int rK = ((sr >> 5) & 1)*32 + ((sr >> 2) & 1)*16 + ((sr >> 3) & 3)*4 + (sr & 3);
  const short* kp = kb + (size_t)bh*NN*HDIM + (size_t)sr*HDIM + sc;
  const short* vp = vtb + ((size_t)bh*HDIM + sr)*NN + sc;
  const float* mb = mbias + b*NN;

  s16x8 kr0 = *(const s16x8*)(kp);
  s16x8 kr1 = *(const s16x8*)(kp + 8);
  s16x8 vr0 = *(const s16x8*)(vp);
  s16x8 vr1 = *(const s16x8*)(vp + 8);
  *(s16x8*)&Kt[0][rK*72 + sc]     = kr0;
  *(s16x8*)&Kt[0][rK*72 + sc + 8] = kr1;
  *(s16x8*)&Vt[0][sr*72 + sc]     = vr0;
  *(s16x8*)&Vt[0][sr*72 + sc + 8] = vr1;
  __syncthreads();

  int cur = 0;
  for (int k0 = 0; k0 < NN; k0 += 64) {
    const bool nl = (k0 + 64 < NN);
    if (nl) {
      kp += 64*HDIM; vp += 64;
      kr0 = *(const s16x8*)(kp);
      kr1 = *(const s16x8*)(kp + 8);
      vr0 = *(const s16x8*)(vp);
      vr1 = *(const s16x8*)(vp + 8);
    }
    const short* KtC = Kt[cur];
    const short* VtC = Vt[cur];

    f32x4 sA[4], sB[4];
    __builtin_amdgcn_s_setprio(1);
#pragma unroll
    for (int j = 0; j < 4; ++j) {
      s16x8 ka0 = *(const s16x8*)&KtC[(j*16 + lr)*72 + g*8];
      s16x8 ka1 = *(const s16x8*)&KtC[(j*16 + lr)*72 + 32 + g*8];
      sA[j] = mfma16(ka1, qfA1, mfma16(ka0, qfA0, zf4()));
      sB[j] = mfma16(ka1, qfB1, mfma16(ka0, qfB0, zf4()));
    }
    __builtin_amdgcn_s_setprio(0);

    if (segbits & (1u << (k0 >> 6))) {
#pragma unroll
      for (int j = 0; j < 4; ++j) {
        f32x4 bi = *(const f32x4*)&mb[k0 + (j >> 1)*32 + (j & 1)*4 + g*8];
#pragma unroll
        for (int r = 0; r < 4; ++r) { sA[j][r] += bi[r]; sB[j][r] += bi[r]; }
      }
    }

    float a0 = vmax3(sA[0][0], sA[0][1], sA[0][2]);
    float a1 = vmax3(sA[0][3], sA[1][0], sA[1][1]);
    float a2 = vmax3(sA[1][2], sA[1][3], sA[2][0]);
    float a3 = vmax3(sA[2][1], sA[2][2], sA[2][3]);
    float a4 = vmax3(sA[3][0], sA[3][1], sA[3][2]);
    float lmaxA = fmaxf(vmax3(a0, a1, a2), vmax3(a3, a4, sA[3][3]));
    float b0 = vmax3(sB[0][0], sB[0][1], sB[0][2]);
    float b1 = vmax3(sB[0][3], sB[1][0], sB[1][1]);
    float b2 = vmax3(sB[1][2], sB[1][3], sB[2][0]);
    float b3 = vmax3(sB[2][1], sB[2][2], sB[2][3]);
    float b4 = vmax3(sB[3][0], sB[3][1], sB[3][2]);
    float lmaxB = fmaxf(vmax3(b0, b1, b2), vmax3(b3, b4, sB[3][3]));

    if (__any(lmaxA > mrunA + 8.f)) {
      float rmax = fmaxf(lmaxA, __shfl_xor(lmaxA, 16));
      rmax = fmaxf(rmax, __shfl_xor(rmax, 32));
      float mnew = fmaxf(mrunA, rmax);
      float al = vexp2(mrunA - mnew);
      mrunA = mnew;
      float alr[4];
#pragma unroll
      for (int r = 0; r < 4; ++r)
        alr[r] = __shfl(al, (lane & 48) | (g*4 + r));
#pragma unroll
      for (int r = 0; r < 4; ++r) {
        accA[0][r] *= alr[r]; accA[1][r] *= alr[r];
        accA[2][r] *= alr[r]; accA[3][r] *= alr[r];
        acclA[r]   *= alr[r];
      }
    }
    if (__any(lmaxB > mrunB + 8.f)) {
      float rmax = fmaxf(lmaxB, __shfl_xor(lmaxB, 16));
      rmax = fmaxf(rmax, __shfl_xor(rmax, 32));
      float mnew = fmaxf(mrunB, rmax);
      float al = vexp2(mrunB - mnew);
      mrunB = mnew;
      float alr[4];
#pragma unroll
      for (int r = 0; r < 4; ++r)
        alr[r] = __shfl(al, (lane & 48) | (g*4 + r));
#pragma unroll
      for (int r = 0; r < 4; ++r) {
        accB[0][r] *= alr[r]; accB[1][r] *= alr[r];
        accB[2][r] *= alr[r]; accB[3][r] *= alr[r];
        acclB[r]   *= alr[r];
      }
    }

    union { unsigned u[4]; s16x8 v; } A0, A1, B0, B1;
    {
      float p[4][4];
#pragma unroll
      for (int j = 0; j < 4; ++j) {
        p[j][0] = vexp2(sA[j][0] - mrunA);
        p[j][1] = vexp2(sA[j][1] - mrunA);
        p[j][2] = vexp2(sA[j][2] - mrunA);
        p[j][3] = vexp2(sA[j][3] - mrunA);
      }
      A0.u[0] = cvtpk_bf16(p[0][0], p[0][1]);
      A0.u[1] = cvtpk_bf16(p[0][2], p[0][3]);
      A0.u[2] = cvtpk_bf16(p[1][0], p[1][1]);
      A0.u[3] = cvtpk_bf16(p[1][2], p[1][3]);
      A1.u[0] = cvtpk_bf16(p[2][0], p[2][1]);
      A1.u[1] = cvtpk_bf16(p[2][2], p[2][3]);
      A1.u[2] = cvtpk_bf16(p[3][0], p[3][1]);
      A1.u[3] = cvtpk_bf16(p[3][2], p[3][3]);
    }
    {
      float p[4][4];
#pragma unroll
      for (int j = 0; j < 4; ++j) {
        p[j][0] = vexp2(sB[j][0] - mrunB);
        p[j][1] = vexp2(sB[j][1] - mrunB);
        p[j][2] = vexp2(sB[j][2] - mrunB);
        p[j][3] = vexp2(sB[j][3] - mrunB);
      }
      B0.u[0] = cvtpk_bf16(p[0][0], p[0][1]);
      B0.u[1] = cvtpk_bf16(p[0][2], p[0][3]);
      B0.u[2] = cvtpk_bf16(p[1][0], p[1][1]);
      B0.u[3] = cvtpk_bf16(p[1][2], p[1][3]);
      B1.u[0] = cvtpk_bf16(p[2][0], p[2][1]);
      B1.u[1] = cvtpk_bf16(p[2][2], p[2][3]);
      B1.u[2] = cvtpk_bf16(p[3][0], p[3][1]);
      B1.u[3] = cvtpk_bf16(p[3][2], p[3][3]);
    }

    // EARLY staging writes: target buf^1 (PV below reads buf) — latency hides under PV
    if (nl) {
      *(s16x8*)&Kt[cur^1][rK*72 + sc]     = kr0;
      *(s16x8*)&Kt[cur^1][rK*72 + sc + 8] = kr1;
      *(s16x8*)&Vt[cur^1][sr*72 + sc]     = vr0;
      *(s16x8*)&Vt[cur^1][sr*72 + sc + 8] = vr1;
    }

    __builtin_amdgcn_s_setprio(1);
    acclA = mfma16(A0.v, one8, acclA);
    acclA = mfma16(A1.v, one8, acclA);
    acclB = mfma16(B0.v, one8, acclB);
    acclB = mfma16(B1.v, one8, acclB);
#pragma unroll
    for (int db = 0; db < 4; ++db) {
      s16x8 vb0 = *(const s16x8*)&VtC[(db*16 + lr)*72 + g*8];
      s16x8 vb1 = *(const s16x8*)&VtC[(db*16 + lr)*72 + 32 + g*8];
      accA[db] = mfma16(A0.v, vb0, accA[db]);
      accA[db] = mfma16(A1.v, vb1, accA[db]);
      accB[db] = mfma16(B0.v, vb0, accB[db]);
      accB[db] = mfma16(B1.v, vb1, accB[db]);
    }
    __builtin_amdgcn_s_setprio(0);

    if (nl) {
      __syncthreads();
      cur ^= 1;
    }
  }

#pragma unroll
  for (int r = 0; r < 4; ++r) {
    float invA = vrcp(acclA[r]);
    float invB = vrcp(acclB[r]);
    size_t rowA = (size_t)(b*NN + q0 + g*4 + r);
    size_t rowB = rowA + 16;
#pragma unroll
    for (int db = 0; db < 4; ++db) {
      attnb[rowA*HH + (bh & 15)*64 + db*16 + lr] = f2bf(accA[db][r]*invA);
      attnb[rowB*HH + (bh & 15)*64 + db*16 + lr] = f2bf(accB[db][r]*invB);
    }
  }
}

// ---------------- output projection (fp32 out) ----------------
__global__ __launch_bounds__(256) void outproj_kernel(
    const short* __restrict__ attnb, const short* __restrict__ wob,
    float* __restrict__ out) {
  __shared__ short smem[16384];
  const int bm = blockIdx.y, bn = blockIdx.x;
  f32x4 acc[4][4];
  gemm128_core(attnb, wob, bm, bn, smem, acc);
  const int tid = threadIdx.x, lane = tid & 63, wid = tid >> 6;
  const int wr = wid >> 1, wc = wid & 1, g = lane >> 4, lr = lane & 15;
  const int m0 = bm*128 + wr*64;
  const int c0 = bn*128 + wc*64;
#pragma unroll
  for (int mf = 0; mf < 4; ++mf)
#pragma unroll
    for (int r = 0; r < 4; ++r) {
      int m = m0 + mf*16 + g*4 + r;
      float* po = out + (size_t)m*HH + c0;
#pragma unroll
      for (int nf = 0; nf < 4; ++nf)
        po[nf*16 + lr] = acc[mf][nf][r];
    }
}

extern "C" void kernel_launch(void* const* d_in, const int* in_sizes, int n_in,
                              void* d_out, int out_size, void* d_ws, size_t ws_size,
                              hipStream_t stream) {
  const float* feat = (const float*)d_in[0];
  const int*   mask = (const int*)d_in[1];
  const float* wq   = (const float*)d_in[2];
  const float* wk   = (const float*)d_in[3];
  const float* wv   = (const float*)d_in[4];
  const float* wo   = (const float*)d_in[5];
  float* out = (float*)d_out;

  char* ws = (char*)d_ws;
  size_t off = 0;
  short* fbf = (short*)(ws + off); off += (size_t)BB*NN*HH*2;
  short* wqb = (short*)(ws + off); off += (size_t)HH*HH*2;
  short* wkb = (short*)(ws + off); off += (size_t)HH*HH*2;
  short* wvb = (short*)(ws + off); off += (size_t)HH*HH*2;
  short* wob = (short*)(ws + off); off += (size_t)HH*HH*2;
  float* cosb = (float*)(ws + off); off += (size_t)NN*32*4;
  float* sinb = (float*)(ws + off); off += (size_t)NN*32*4;
  float* mbias = (float*)(ws + off); off += (size_t)BB*NN*4;
  int* msegb = (int*)(ws + off); off += (size_t)BB*(NN/64)*4;
  short* qbuf = (short*)(ws + off); off += (size_t)BB*NN*HH*2;
  short* kbuf = (short*)(ws + off); off += (size_t)BB*NN*HH*2;
  short* vtbuf = (short*)(ws + off); off += (size_t)BB*NN*HH*2;
  short* attnb = (short*)(ws + off); off += (size_t)BB*NN*HH*2;

  prep_kernel<<<1024, 256, 0, stream>>>(feat, mask, wq, wk, wv, wo,
                                        fbf, wqb, wkb, wvb, wob, cosb, sinb,
                                        mbias, msegb);
  qkv_kernel<<<dim3(HH/128, BB*NN/256, 3), 256, 0, stream>>>(
      fbf, wqb, wkb, wvb, cosb, sinb, qbuf, kbuf, vtbuf);
  attn_kernel<<<512, 256, 0, stream>>>(
      qbuf, kbuf, vtbuf, mbias, msegb, attnb);
  outproj_kernel<<<dim3(HH/128, BB*NN/128), 256, 0, stream>>>(attnb, wob, out);
}

// Round 13
// 122.651 us; speedup vs baseline: 1.2278x; 1.2278x over previous
//
#include <hip/hip_runtime.h>
#include <hip/hip_bf16.h>

typedef __attribute__((ext_vector_type(4))) float f32x4;
typedef __attribute__((ext_vector_type(8))) short s16x8;
typedef __attribute__((ext_vector_type(4))) short s16x4;

#define BB 2
#define NN 2048
#define HH 1024
#define NHEAD 16
#define HDIM 64

__device__ __forceinline__ short f2bf(float f) {
  union { float f; unsigned u; } v; v.f = f;
  unsigned r = v.u + 0x7fffu + ((v.u >> 16) & 1u);
  return (short)(r >> 16);
}

__device__ __forceinline__ f32x4 zf4() { f32x4 z; z[0]=0.f; z[1]=0.f; z[2]=0.f; z[3]=0.f; return z; }

__device__ __forceinline__ f32x4 mfma16(s16x8 a, s16x8 b, f32x4 c) {
  return __builtin_amdgcn_mfma_f32_16x16x32_bf16(a, b, c, 0, 0, 0);
}

__device__ __forceinline__ s16x4 cvt4(f32x4 v) {
  s16x4 o; o[0]=f2bf(v[0]); o[1]=f2bf(v[1]); o[2]=f2bf(v[2]); o[3]=f2bf(v[3]); return o;
}

__device__ __forceinline__ float vexp2(float x) {
  float r; asm("v_exp_f32 %0, %1" : "=v"(r) : "v"(x)); return r;
}

__device__ __forceinline__ float vrcp(float x) {
  float r; asm("v_rcp_f32 %0, %1" : "=v"(r) : "v"(x)); return r;
}

__device__ __forceinline__ float vmax3(float a, float b, float c) {
  float r; asm("v_max3_f32 %0, %1, %2, %3" : "=v"(r) : "v"(a), "v"(b), "v"(c)); return r;
}

__device__ __forceinline__ unsigned cvtpk_bf16(float lo, float hi) {
  unsigned r; asm("v_cvt_pk_bf16_f32 %0, %1, %2" : "=v"(r) : "v"(lo), "v"(hi)); return r;
}

// async global->LDS, 16B per lane; lds ptr must be wave-uniform base (HW adds lane*16)
__device__ __forceinline__ void gload_lds16(const short* g, short* l) {
  __builtin_amdgcn_global_load_lds(
      (const __attribute__((address_space(1))) unsigned*)g,
      (__attribute__((address_space(3))) unsigned*)l, 16, 0, 0);
}

// ---------------- prep: fp32->bf16 conversions + rope tables + mask bias ----------------
__global__ __launch_bounds__(256) void prep_kernel(
    const float* __restrict__ feat, const int* __restrict__ mask,
    const float* __restrict__ wq, const float* __restrict__ wk,
    const float* __restrict__ wv, const float* __restrict__ wo,
    short* __restrict__ fbf, short* __restrict__ wqb, short* __restrict__ wkb,
    short* __restrict__ wvb, short* __restrict__ wob,
    float* __restrict__ cosb, float* __restrict__ sinb,
    float* __restrict__ mbias, int* __restrict__ mseg) {
  const int tid = blockIdx.x * blockDim.x + threadIdx.x;
  const int nth = gridDim.x * blockDim.x;
  const int NF4 = BB*NN*HH/4;
  for (int i = tid; i < NF4; i += nth)
    ((s16x4*)fbf)[i] = cvt4(((const f32x4*)feat)[i]);
  const int NW4 = HH*HH/4;
  for (int i = tid; i < NW4; i += nth) {
    ((s16x4*)wqb)[i] = cvt4(((const f32x4*)wq)[i]);
    ((s16x4*)wkb)[i] = cvt4(((const f32x4*)wk)[i]);
    ((s16x4*)wvb)[i] = cvt4(((const f32x4*)wv)[i]);
    ((s16x4*)wob)[i] = cvt4(((const f32x4*)wo)[i]);
  }
  // rope table: cos/sin[pos][f], f in [0,32), inv_freq = 10000^(-f/32)
  for (int i = tid; i < NN*32; i += nth) {
    int pos = i >> 5, f = i & 31;
    float inv = __expf(-(float)f * 0.28782313662425572f);  // ln(10000)/32
    float ang = (float)pos * inv;
    float s, c;
    sincosf(ang, &s, &c);
    cosb[i] = c; sinb[i] = s;
  }
  // mask bias: 0 if valid, -1e30 if masked (finite so s-m never cancels to 0)
  for (int i = tid; i < BB*NN; i += nth)
    mbias[i] = mask[i] ? 0.f : -1.0e30f;
  // per-64-key segment flag: 1 if ANY key in segment is masked
  for (int i = tid; i < BB*(NN/64); i += nth) {
    int bb = i / (NN/64), sg = i % (NN/64);
    int any = 0;
    for (int j = 0; j < 64; ++j) any |= (mask[bb*NN + sg*64 + j] == 0);
    mseg[i] = any;
  }
}

// ---------------- GEMM core: C = A(bf16 [M,1024]) @ W^T ----------------
// 256 threads, tile 128x128, BK=32, waves 2x2, per-wave 64x64 (4x4 frags of 16x16x32)
// global_load_lds staging, double-buffered linear LDS
__device__ __forceinline__ void gemm128_core(
    const short* __restrict__ A, const short* __restrict__ W,
    int bm, int bn, short* smem, f32x4 acc[4][4]) {
  const int tid = threadIdx.x;
  const int lane = tid & 63, wid = tid >> 6;
  const int wr = wid >> 1, wc = wid & 1;
  const int g = lane >> 4, lr = lane & 15;
#pragma unroll
  for (int i = 0; i < 4; ++i)
#pragma unroll
    for (int j = 0; j < 4; ++j) acc[i][j] = zf4();

  const int srow = wid*16 + (lane >> 2);
  const int scol = (lane & 3) * 8;
  const short* Abase = A + (size_t)(bm*128 + srow)*HH + scol;
  const short* Wbase = W + (size_t)(bn*128 + srow)*HH + scol;

  auto stage = [&](int b, int t) {
    const short* ga = Abase + t*32;
    const short* gb = Wbase + t*32;
    short* la = smem + b*8192 + wid*512;          // wave-uniform LDS base
    short* lb = smem + b*8192 + 4096 + wid*512;
    gload_lds16(ga,          la);
    gload_lds16(ga + 64*HH,  la + 2048);
    gload_lds16(gb,          lb);
    gload_lds16(gb + 64*HH,  lb + 2048);
  };

  stage(0, 0);
  asm volatile("s_waitcnt vmcnt(0)");
  __syncthreads();

  const int NT = HH / 32;
  int cur = 0;
  for (int t = 0; t < NT; ++t) {
    if (t + 1 < NT) stage(cur ^ 1, t + 1);  // async loads overlap MFMA below
    const short* At = smem + cur*8192;
    const short* Bt = At + 4096;
    s16x8 af[4], bf[4];
#pragma unroll
    for (int mf = 0; mf < 4; ++mf)
      af[mf] = *(const s16x8*)&At[(wr*64 + mf*16 + lr)*32 + g*8];
#pragma unroll
    for (int nf = 0; nf < 4; ++nf)
      bf[nf] = *(const s16x8*)&Bt[(wc*64 + nf*16 + lr)*32 + g*8];
#pragma unroll
    for (int mf = 0; mf < 4; ++mf)
#pragma unroll
      for (int nf = 0; nf < 4; ++nf)
        acc[mf][nf] = mfma16(af[mf], bf[nf], acc[mf][nf]);
    __syncthreads();  // barrier drain completes the staged loads for next iter
    cur ^= 1;
  }
}

// ---------------- QKV projection + RoPE + layout ----------------
// 1-D grid of 768 blocks, XCD-chunked: xcd = l&7; all 8 bn-blocks of a (bm,z)
// combo land on ONE XCD so the A-panel (256KB) is fetched into one L2 and reused
// 8x (12 combos/XCD -> 3MB A working set < 4MB L2).
// z=0: Q (rope, *0.125*log2e) -> [b,h,n,d] ; z=1: K (rope) -> [b,h,n,d] ; z=2: V -> V^T [b,h,d,n]
__global__ __launch_bounds__(256) void qkv_kernel(
    const short* __restrict__ fbf, const short* __restrict__ wqb,
    const short* __restrict__ wkb, const short* __restrict__ wvb,
    const float* __restrict__ cosb, const float* __restrict__ sinb,
    short* __restrict__ qb, short* __restrict__ kb, short* __restrict__ vtb) {
  __shared__ short smem[18432];
  const int l = blockIdx.x;
  const int xcd = l & 7, j = l >> 3;        // j in [0,96)
  const int bn = j & 7;
  const int cg = xcd*12 + (j >> 3);         // combo id in [0,96)
  const int bm = cg & 31, z = cg >> 5;      // 32 bm x 3 z
  const short* W = (z == 0) ? wqb : ((z == 1) ? wkb : wvb);
  f32x4 acc[4][4];
  gemm128_core(fbf, W, bm, bn, smem, acc);

  const int tid = threadIdx.x, lane = tid & 63, wid = tid >> 6;
  const int wr = wid >> 1, wc = wid & 1, g = lane >> 4, lr = lane & 15;
  const int head = bn*2 + wc;
  const int m0 = bm*128 + wr*64;
  const int b = m0 / NN;

  if (z < 2) {
    short* dst = (z == 0) ? qb : kb;
    // Q: fold 1/sqrt(d) AND log2(e) (we use exp2 in attention)
    const float scale = (z == 0) ? 0.18033688011112042f : 1.0f;
#pragma unroll
    for (int mf = 0; mf < 4; ++mf) {
#pragma unroll
      for (int r = 0; r < 4; ++r) {
        int m = m0 + mf*16 + g*4 + r;
        int n = m & (NN - 1);
        float c0 = cosb[n*32 + lr],      s0 = sinb[n*32 + lr];
        float c1 = cosb[n*32 + 16 + lr], s1 = sinb[n*32 + 16 + lr];
        float v0 = acc[mf][0][r], v1 = acc[mf][1][r];
        float v2 = acc[mf][2][r], v3 = acc[mf][3][r];
        float o0 = (v0*c0 - v2*s0) * scale;
        float o1 = (v1*c1 - v3*s1) * scale;
        float o2 = (v2*c0 + v0*s0) * scale;
        float o3 = (v3*c1 + v1*s1) * scale;
        size_t base = ((size_t)(b*NHEAD + head)*NN + n)*HDIM;
        dst[base +  0 + lr] = f2bf(o0);
        dst[base + 16 + lr] = f2bf(o1);
        dst[base + 32 + lr] = f2bf(o2);
        dst[base + 48 + lr] = f2bf(o3);
      }
    }
  } else {
    __syncthreads();
    short* tp = smem + wid*4608;  // [64][72]
#pragma unroll
    for (int mf = 0; mf < 4; ++mf)
#pragma unroll
      for (int nf = 0; nf < 4; ++nf)
#pragma unroll
        for (int r = 0; r < 4; ++r)
          tp[(nf*16 + lr)*72 + mf*16 + g*4 + r] = f2bf(acc[mf][nf][r]);
    __syncthreads();
    const int nbase = m0 & (NN - 1);
    size_t vbase = ((size_t)(b*NHEAD + head)*HDIM)*NN;
#pragma unroll
    for (int it = 0; it < 8; ++it) {
      int jj = it*8 + (lane >> 3);
      int ns = (lane & 7)*8;
      s16x8 vv = *(const s16x8*)&tp[jj*72 + ns];
      *(s16x8*)&vtb[vbase + (size_t)jj*NN + nbase + ns] = vv;
    }
  }
}

// ---------------- fused flash attention (round-10 verified: 61.2us) ----------------
// QBLK=128, 32 q/wave (2 q-groups), XCD-pinned swizzle, permuted K staging (P in regs),
// ones-MFMA lsum, vcc-only defer-max, K/V LDS dbuf with early writes, 1 barrier/step.
__global__ __launch_bounds__(256) void attn_kernel(
    const short* __restrict__ qb, const short* __restrict__ kb,
    const short* __restrict__ vtb, const float* __restrict__ mbias,
    const int* __restrict__ mseg,
    short* __restrict__ attnb) {
  __shared__ short Kt[2][64*72];   // [buf][perm key][64 d + pad]
  __shared__ short Vt[2][64*72];   // [buf][64 d][64 keys + pad]
  const int tid = threadIdx.x, lane = tid & 63, wid = tid >> 6;
  const int g = lane >> 4, lr = lane & 15;
  const int w = blockIdx.x;
  const int bh = (w & 7)*4 + ((w >> 3) & 3);
  const int qt = w >> 5;
  const int b = bh >> 4;
  const int q0 = qt*128 + wid*32;

  const short* qpA = qb + ((size_t)bh*NN + q0 + lr)*HDIM + g*8;
  s16x8 qfA0 = *(const s16x8*)(qpA);
  s16x8 qfA1 = *(const s16x8*)(qpA + 32);
  const short* qpB = qpA + 16*HDIM;
  s16x8 qfB0 = *(const s16x8*)(qpB);
  s16x8 qfB1 = *(const s16x8*)(qpB + 32);

  s16x8 one8;
#pragma unroll
  for (int i = 0; i < 8; ++i) one8[i] = (short)0x3F80;  // bf16 1.0

  f32x4 accA[4], accB[4];
#pragma unroll
  for (int i = 0; i < 4; ++i) { accA[i] = zf4(); accB[i] = zf4(); }
  f32x4 acclA = zf4(), acclB = zf4();
  float mrunA = -3.0e38f, mrunB = -3.0e38f;

  const int* msp = mseg + b*(NN/64);
  int segflag = (lane < 32) ? msp[lane] : 0;
  unsigned segbits = (unsigned)__ballot(segflag != 0);

  const int sr = tid >> 2;
  const int sc = (tid & 3) * 16;
  const int rK = ((sr >> 5) & 1)*32 + ((sr >> 2) & 1)*16 + ((sr >> 3) & 3)*4 + (sr & 3);
  const short* kp = kb + (size_t)bh*NN*HDIM + (size_t)sr*HDIM + sc;
  const short* vp = vtb + ((size_t)bh*HDIM + sr)*NN + sc;
  const float* mb = mbias + b*NN;

  s16x8 kr0 = *(const s16x8*)(kp);
  s16x8 kr1 = *(const s16x8*)(kp + 8);
  s16x8 vr0 = *(const s16x8*)(vp);
  s16x8 vr1 = *(const s16x8*)(vp + 8);
  *(s16x8*)&Kt[0][rK*72 + sc]     = kr0;
  *(s16x8*)&Kt[0][rK*72 + sc + 8] = kr1;
  *(s16x8*)&Vt[0][sr*72 + sc]     = vr0;
  *(s16x8*)&Vt[0][sr*72 + sc + 8] = vr1;
  __syncthreads();

  int cur = 0;
  for (int k0 = 0; k0 < NN; k0 += 64) {
    const bool nl = (k0 + 64 < NN);
    if (nl) {
      kp += 64*HDIM; vp += 64;
      kr0 = *(const s16x8*)(kp);
      kr1 = *(const s16x8*)(kp + 8);
      vr0 = *(const s16x8*)(vp);
      vr1 = *(const s16x8*)(vp + 8);
    }
    const short* KtC = Kt[cur];
    const short* VtC = Vt[cur];

    f32x4 sA[4], sB[4];
    __builtin_amdgcn_s_setprio(1);
#pragma unroll
    for (int j = 0; j < 4; ++j) {
      s16x8 ka0 = *(const s16x8*)&KtC[(j*16 + lr)*72 + g*8];
      s16x8 ka1 = *(const s16x8*)&KtC[(j*16 + lr)*72 + 32 + g*8];
      sA[j] = mfma16(ka1, qfA1, mfma16(ka0, qfA0, zf4()));
      sB[j] = mfma16(ka1, qfB1, mfma16(ka0, qfB0, zf4()));
    }
    __builtin_amdgcn_s_setprio(0);

    if (segbits & (1u << (k0 >> 6))) {
#pragma unroll
      for (int j = 0; j < 4; ++j) {
        f32x4 bi = *(const f32x4*)&mb[k0 + (j >> 1)*32 + (j & 1)*4 + g*8];
#pragma unroll
        for (int r = 0; r < 4; ++r) { sA[j][r] += bi[r]; sB[j][r] += bi[r]; }
      }
    }

    float a0 = vmax3(sA[0][0], sA[0][1], sA[0][2]);
    float a1 = vmax3(sA[0][3], sA[1][0], sA[1][1]);
    float a2 = vmax3(sA[1][2], sA[1][3], sA[2][0]);
    float a3 = vmax3(sA[2][1], sA[2][2], sA[2][3]);
    float a4 = vmax3(sA[3][0], sA[3][1], sA[3][2]);
    float lmaxA = fmaxf(vmax3(a0, a1, a2), vmax3(a3, a4, sA[3][3]));
    float b0 = vmax3(sB[0][0], sB[0][1], sB[0][2]);
    float b1 = vmax3(sB[0][3], sB[1][0], sB[1][1]);
    float b2 = vmax3(sB[1][2], sB[1][3], sB[2][0]);
    float b3 = vmax3(sB[2][1], sB[2][2], sB[2][3]);
    float b4 = vmax3(sB[3][0], sB[3][1], sB[3][2]);
    float lmaxB = fmaxf(vmax3(b0, b1, b2), vmax3(b3, b4, sB[3][3]));

    if (__any(lmaxA > mrunA + 8.f)) {
      float rmax = fmaxf(lmaxA, __shfl_xor(lmaxA, 16));
      rmax = fmaxf(rmax, __shfl_xor(rmax, 32));
      float mnew = fmaxf(mrunA, rmax);
      float al = vexp2(mrunA - mnew);
      mrunA = mnew;
      float alr[4];
#pragma unroll
      for (int r = 0; r < 4; ++r)
        alr[r] = __shfl(al, (lane & 48) | (g*4 + r));
#pragma unroll
      for (int r = 0; r < 4; ++r) {
        accA[0][r] *= alr[r]; accA[1][r] *= alr[r];
        accA[2][r] *= alr[r]; accA[3][r] *= alr[r];
        acclA[r]   *= alr[r];
      }
    }
    if (__any(lmaxB > mrunB + 8.f)) {
      float rmax = fmaxf(lmaxB, __shfl_xor(lmaxB, 16));
      rmax = fmaxf(rmax, __shfl_xor(rmax, 32));
      float mnew = fmaxf(mrunB, rmax);
      float al = vexp2(mrunB - mnew);
      mrunB = mnew;
      float alr[4];
#pragma unroll
      for (int r = 0; r < 4; ++r)
        alr[r] = __shfl(al, (lane & 48) | (g*4 + r));
#pragma unroll
      for (int r = 0; r < 4; ++r) {
        accB[0][r] *= alr[r]; accB[1][r] *= alr[r];
        accB[2][r] *= alr[r]; accB[3][r] *= alr[r];
        acclB[r]   *= alr[r];
      }
    }

    union { unsigned u[4]; s16x8 v; } A0, A1, B0, B1;
    {
      float p[4][4];
#pragma unroll
      for (int j = 0; j < 4; ++j) {
        p[j][0] = vexp2(sA[j][0] - mrunA);
        p[j][1] = vexp2(sA[j][1] - mrunA);
        p[j][2] = vexp2(sA[j][2] - mrunA);
        p[j][3] = vexp2(sA[j][3] - mrunA);
      }
      A0.u[0] = cvtpk_bf16(p[0][0], p[0][1]);
      A0.u[1] = cvtpk_bf16(p[0][2], p[0][3]);
      A0.u[2] = cvtpk_bf16(p[1][0], p[1][1]);
      A0.u[3] = cvtpk_bf16(p[1][2], p[1][3]);
      A1.u[0] = cvtpk_bf16(p[2][0], p[2][1]);
      A1.u[1] = cvtpk_bf16(p[2][2], p[2][3]);
      A1.u[2] = cvtpk_bf16(p[3][0], p[3][1]);
      A1.u[3] = cvtpk_bf16(p[3][2], p[3][3]);
    }
    {
      float p[4][4];
#pragma unroll
      for (int j = 0; j < 4; ++j) {
        p[j][0] = vexp2(sB[j][0] - mrunB);
        p[j][1] = vexp2(sB[j][1] - mrunB);
        p[j][2] = vexp2(sB[j][2] - mrunB);
        p[j][3] = vexp2(sB[j][3] - mrunB);
      }
      B0.u[0] = cvtpk_bf16(p[0][0], p[0][1]);
      B0.u[1] = cvtpk_bf16(p[0][2], p[0][3]);
      B0.u[2] = cvtpk_bf16(p[1][0], p[1][1]);
      B0.u[3] = cvtpk_bf16(p[1][2], p[1][3]);
      B1.u[0] = cvtpk_bf16(p[2][0], p[2][1]);
      B1.u[1] = cvtpk_bf16(p[2][2], p[2][3]);
      B1.u[2] = cvtpk_bf16(p[3][0], p[3][1]);
      B1.u[3] = cvtpk_bf16(p[3][2], p[3][3]);
    }

    // EARLY staging writes: target buf^1 (PV below reads buf) — latency hides under PV
    if (nl) {
      *(s16x8*)&Kt[cur^1][rK*72 + sc]     = kr0;
      *(s16x8*)&Kt[cur^1][rK*72 + sc + 8] = kr1;
      *(s16x8*)&Vt[cur^1][sr*72 + sc]     = vr0;
      *(s16x8*)&Vt[cur^1][sr*72 + sc + 8] = vr1;
    }

    __builtin_amdgcn_s_setprio(1);
    acclA = mfma16(A0.v, one8, acclA);
    acclA = mfma16(A1.v, one8, acclA);
    acclB = mfma16(B0.v, one8, acclB);
    acclB = mfma16(B1.v, one8, acclB);
#pragma unroll
    for (int db = 0; db < 4; ++db) {
      s16x8 vb0 = *(const s16x8*)&VtC[(db*16 + lr)*72 + g*8];
      s16x8 vb1 = *(const s16x8*)&VtC[(db*16 + lr)*72 + 32 + g*8];
      accA[db] = mfma16(A0.v, vb0, accA[db]);
      accA[db] = mfma16(A1.v, vb1, accA[db]);
      accB[db] = mfma16(B0.v, vb0, accB[db]);
      accB[db] = mfma16(B1.v, vb1, accB[db]);
    }
    __builtin_amdgcn_s_setprio(0);

    if (nl) {
      __syncthreads();
      cur ^= 1;
    }
  }

#pragma unroll
  for (int r = 0; r < 4; ++r) {
    float invA = vrcp(acclA[r]);
    float invB = vrcp(acclB[r]);
    size_t rowA = (size_t)(b*NN + q0 + g*4 + r);
    size_t rowB = rowA + 16;
#pragma unroll
    for (int db = 0; db < 4; ++db) {
      attnb[rowA*HH + (bh & 15)*64 + db*16 + lr] = f2bf(accA[db][r]*invA);
      attnb[rowB*HH + (bh & 15)*64 + db*16 + lr] = f2bf(accB[db][r]*invB);
    }
  }
}

// ---------------- output projection (fp32 out) ----------------
__global__ __launch_bounds__(256) void outproj_kernel(
    const short* __restrict__ attnb, const short* __restrict__ wob,
    float* __restrict__ out) {
  __shared__ short smem[16384];
  const int bm = blockIdx.y, bn = blockIdx.x;
  f32x4 acc[4][4];
  gemm128_core(attnb, wob, bm, bn, smem, acc);
  const int tid = threadIdx.x, lane = tid & 63, wid = tid >> 6;
  const int wr = wid >> 1, wc = wid & 1, g = lane >> 4, lr = lane & 15;
  const int m0 = bm*128 + wr*64;
  const int c0 = bn*128 + wc*64;
#pragma unroll
  for (int mf = 0; mf < 4; ++mf)
#pragma unroll
    for (int r = 0; r < 4; ++r) {
      int m = m0 + mf*16 + g*4 + r;
      float* po = out + (size_t)m*HH + c0;
#pragma unroll
      for (int nf = 0; nf < 4; ++nf)
        po[nf*16 + lr] = acc[mf][nf][r];
    }
}

extern "C" void kernel_launch(void* const* d_in, const int* in_sizes, int n_in,
                              void* d_out, int out_size, void* d_ws, size_t ws_size,
                              hipStream_t stream) {
  const float* feat = (const float*)d_in[0];
  const int*   mask = (const int*)d_in[1];
  const float* wq   = (const float*)d_in[2];
  const float* wk   = (const float*)d_in[3];
  const float* wv   = (const float*)d_in[4];
  const float* wo   = (const float*)d_in[5];
  float* out = (float*)d_out;

  char* ws = (char*)d_ws;
  size_t off = 0;
  short* fbf = (short*)(ws + off); off += (size_t)BB*NN*HH*2;
  short* wqb = (short*)(ws + off); off += (size_t)HH*HH*2;
  short* wkb = (short*)(ws + off); off += (size_t)HH*HH*2;
  short* wvb = (short*)(ws + off); off += (size_t)HH*HH*2;
  short* wob = (short*)(ws + off); off += (size_t)HH*HH*2;
  float* cosb = (float*)(ws + off); off += (size_t)NN*32*4;
  float* sinb = (float*)(ws + off); off += (size_t)NN*32*4;
  float* mbias = (float*)(ws + off); off += (size_t)BB*NN*4;
  int* msegb = (int*)(ws + off); off += (size_t)BB*(NN/64)*4;
  short* qbuf = (short*)(ws + off); off += (size_t)BB*NN*HH*2;
  short* kbuf = (short*)(ws + off); off += (size_t)BB*NN*HH*2;
  short* vtbuf = (short*)(ws + off); off += (size_t)BB*NN*HH*2;
  short* attnb = (short*)(ws + off); off += (size_t)BB*NN*HH*2;

  prep_kernel<<<1024, 256, 0, stream>>>(feat, mask, wq, wk, wv, wo,
                                        fbf, wqb, wkb, wvb, wob, cosb, sinb,
                                        mbias, msegb);
  qkv_kernel<<<768, 256, 0, stream>>>(
      fbf, wqb, wkb, wvb, cosb, sinb, qbuf, kbuf, vtbuf);
  attn_kernel<<<512, 256, 0, stream>>>(
      qbuf, kbuf, vtbuf, mbias, msegb, attnb);
  outproj_kernel<<<dim3(HH/128, BB*NN/128), 256, 0, stream>>>(attnb, wob, out);
}

// Round 14
// 121.050 us; speedup vs baseline: 1.2440x; 1.0132x over previous
//
#include <hip/hip_runtime.h>
#include <hip/hip_bf16.h>

typedef __attribute__((ext_vector_type(4))) float f32x4;
typedef __attribute__((ext_vector_type(8))) short s16x8;
typedef __attribute__((ext_vector_type(4))) short s16x4;

#define BB 2
#define NN 2048
#define HH 1024
#define NHEAD 16
#define HDIM 64

__device__ __forceinline__ short f2bf(float f) {
  union { float f; unsigned u; } v; v.f = f;
  unsigned r = v.u + 0x7fffu + ((v.u >> 16) & 1u);
  return (short)(r >> 16);
}

__device__ __forceinline__ f32x4 zf4() { f32x4 z; z[0]=0.f; z[1]=0.f; z[2]=0.f; z[3]=0.f; return z; }

__device__ __forceinline__ f32x4 mfma16(s16x8 a, s16x8 b, f32x4 c) {
  return __builtin_amdgcn_mfma_f32_16x16x32_bf16(a, b, c, 0, 0, 0);
}

__device__ __forceinline__ s16x4 cvt4(f32x4 v) {
  s16x4 o; o[0]=f2bf(v[0]); o[1]=f2bf(v[1]); o[2]=f2bf(v[2]); o[3]=f2bf(v[3]); return o;
}

__device__ __forceinline__ float vexp2(float x) {
  float r; asm("v_exp_f32 %0, %1" : "=v"(r) : "v"(x)); return r;
}

__device__ __forceinline__ float vrcp(float x) {
  float r; asm("v_rcp_f32 %0, %1" : "=v"(r) : "v"(x)); return r;
}

__device__ __forceinline__ float vmax3(float a, float b, float c) {
  float r; asm("v_max3_f32 %0, %1, %2, %3" : "=v"(r) : "v"(a), "v"(b), "v"(c)); return r;
}

__device__ __forceinline__ unsigned cvtpk_bf16(float lo, float hi) {
  unsigned r; asm("v_cvt_pk_bf16_f32 %0, %1, %2" : "=v"(r) : "v"(lo), "v"(hi)); return r;
}

// async global->LDS, 16B per lane; lds ptr must be wave-uniform base (HW adds lane*16)
__device__ __forceinline__ void gload_lds16(const short* g, short* l) {
  __builtin_amdgcn_global_load_lds(
      (const __attribute__((address_space(1))) unsigned*)g,
      (__attribute__((address_space(3))) unsigned*)l, 16, 0, 0);
}

// ---------------- prep: fp32->bf16 conversions + rope tables + mask bias ----------------
__global__ __launch_bounds__(256) void prep_kernel(
    const float* __restrict__ feat, const int* __restrict__ mask,
    const float* __restrict__ wq, const float* __restrict__ wk,
    const float* __restrict__ wv, const float* __restrict__ wo,
    short* __restrict__ fbf, short* __restrict__ wqb, short* __restrict__ wkb,
    short* __restrict__ wvb, short* __restrict__ wob,
    float* __restrict__ cosb, float* __restrict__ sinb,
    float* __restrict__ mbias, int* __restrict__ mseg) {
  const int tid = blockIdx.x * blockDim.x + threadIdx.x;
  const int nth = gridDim.x * blockDim.x;
  const int NF4 = BB*NN*HH/4;
  for (int i = tid; i < NF4; i += nth)
    ((s16x4*)fbf)[i] = cvt4(((const f32x4*)feat)[i]);
  const int NW4 = HH*HH/4;
  for (int i = tid; i < NW4; i += nth) {
    ((s16x4*)wqb)[i] = cvt4(((const f32x4*)wq)[i]);
    ((s16x4*)wkb)[i] = cvt4(((const f32x4*)wk)[i]);
    ((s16x4*)wvb)[i] = cvt4(((const f32x4*)wv)[i]);
    ((s16x4*)wob)[i] = cvt4(((const f32x4*)wo)[i]);
  }
  // rope table: cos/sin[pos][f], f in [0,32), inv_freq = 10000^(-f/32)
  for (int i = tid; i < NN*32; i += nth) {
    int pos = i >> 5, f = i & 31;
    float inv = __expf(-(float)f * 0.28782313662425572f);  // ln(10000)/32
    float ang = (float)pos * inv;
    float s, c;
    sincosf(ang, &s, &c);
    cosb[i] = c; sinb[i] = s;
  }
  // mask bias: 0 if valid, -1e30 if masked (finite so s-m never cancels to 0)
  for (int i = tid; i < BB*NN; i += nth)
    mbias[i] = mask[i] ? 0.f : -1.0e30f;
  // per-64-key segment flag: 1 if ANY key in segment is masked
  for (int i = tid; i < BB*(NN/64); i += nth) {
    int bb = i / (NN/64), sg = i % (NN/64);
    int any = 0;
    for (int j = 0; j < 64; ++j) any |= (mask[bb*NN + sg*64 + j] == 0);
    mseg[i] = any;
  }
}

// ---------------- GEMM core: C = A(bf16 [M,1024]) @ W^T ----------------
// 256 threads, tile 128x128, BK=32, waves 2x2, per-wave 64x64 (4x4 frags of 16x16x32)
// global_load_lds staging, double-buffered linear LDS
__device__ __forceinline__ void gemm128_core(
    const short* __restrict__ A, const short* __restrict__ W,
    int bm, int bn, short* smem, f32x4 acc[4][4]) {
  const int tid = threadIdx.x;
  const int lane = tid & 63, wid = tid >> 6;
  const int wr = wid >> 1, wc = wid & 1;
  const int g = lane >> 4, lr = lane & 15;
#pragma unroll
  for (int i = 0; i < 4; ++i)
#pragma unroll
    for (int j = 0; j < 4; ++j) acc[i][j] = zf4();

  const int srow = wid*16 + (lane >> 2);
  const int scol = (lane & 3) * 8;
  const short* Abase = A + (size_t)(bm*128 + srow)*HH + scol;
  const short* Wbase = W + (size_t)(bn*128 + srow)*HH + scol;

  auto stage = [&](int b, int t) {
    const short* ga = Abase + t*32;
    const short* gb = Wbase + t*32;
    short* la = smem + b*8192 + wid*512;          // wave-uniform LDS base
    short* lb = smem + b*8192 + 4096 + wid*512;
    gload_lds16(ga,          la);
    gload_lds16(ga + 64*HH,  la + 2048);
    gload_lds16(gb,          lb);
    gload_lds16(gb + 64*HH,  lb + 2048);
  };

  stage(0, 0);
  asm volatile("s_waitcnt vmcnt(0)");
  __syncthreads();

  const int NT = HH / 32;
  int cur = 0;
  for (int t = 0; t < NT; ++t) {
    if (t + 1 < NT) stage(cur ^ 1, t + 1);  // async loads overlap MFMA below
    const short* At = smem + cur*8192;
    const short* Bt = At + 4096;
    s16x8 af[4], bf[4];
#pragma unroll
    for (int mf = 0; mf < 4; ++mf)
      af[mf] = *(const s16x8*)&At[(wr*64 + mf*16 + lr)*32 + g*8];
#pragma unroll
    for (int nf = 0; nf < 4; ++nf)
      bf[nf] = *(const s16x8*)&Bt[(wc*64 + nf*16 + lr)*32 + g*8];
#pragma unroll
    for (int mf = 0; mf < 4; ++mf)
#pragma unroll
      for (int nf = 0; nf < 4; ++nf)
        acc[mf][nf] = mfma16(af[mf], bf[nf], acc[mf][nf]);
    __syncthreads();  // barrier drain completes the staged loads for next iter
    cur ^= 1;
  }
}

// ---------------- QKV projection + RoPE + layout ----------------
// z=0: Q (rope, *0.125*log2e) -> [b,h,n,d] ; z=1: K (rope) -> [b,h,n,d] ; z=2: V -> V^T [b,h,d,n]
__global__ __launch_bounds__(256) void qkv_kernel(
    const short* __restrict__ fbf, const short* __restrict__ wqb,
    const short* __restrict__ wkb, const short* __restrict__ wvb,
    const float* __restrict__ cosb, const float* __restrict__ sinb,
    short* __restrict__ qb, short* __restrict__ kb, short* __restrict__ vtb) {
  __shared__ short smem[18432];
  const int bm = blockIdx.y, bn = blockIdx.x, z = blockIdx.z;
  const short* W = (z == 0) ? wqb : ((z == 1) ? wkb : wvb);
  f32x4 acc[4][4];
  gemm128_core(fbf, W, bm, bn, smem, acc);

  const int tid = threadIdx.x, lane = tid & 63, wid = tid >> 6;
  const int wr = wid >> 1, wc = wid & 1, g = lane >> 4, lr = lane & 15;
  const int head = bn*2 + wc;
  const int m0 = bm*128 + wr*64;
  const int b = m0 / NN;

  if (z < 2) {
    short* dst = (z == 0) ? qb : kb;
    // Q: fold 1/sqrt(d) AND log2(e) (we use exp2 in attention)
    const float scale = (z == 0) ? 0.18033688011112042f : 1.0f;
#pragma unroll
    for (int mf = 0; mf < 4; ++mf) {
#pragma unroll
      for (int r = 0; r < 4; ++r) {
        int m = m0 + mf*16 + g*4 + r;
        int n = m & (NN - 1);
        float c0 = cosb[n*32 + lr],      s0 = sinb[n*32 + lr];
        float c1 = cosb[n*32 + 16 + lr], s1 = sinb[n*32 + 16 + lr];
        float v0 = acc[mf][0][r], v1 = acc[mf][1][r];
        float v2 = acc[mf][2][r], v3 = acc[mf][3][r];
        float o0 = (v0*c0 - v2*s0) * scale;
        float o1 = (v1*c1 - v3*s1) * scale;
        float o2 = (v2*c0 + v0*s0) * scale;
        float o3 = (v3*c1 + v1*s1) * scale;
        size_t base = ((size_t)(b*NHEAD + head)*NN + n)*HDIM;
        dst[base +  0 + lr] = f2bf(o0);
        dst[base + 16 + lr] = f2bf(o1);
        dst[base + 32 + lr] = f2bf(o2);
        dst[base + 48 + lr] = f2bf(o3);
      }
    }
  } else {
    __syncthreads();
    short* tp = smem + wid*4608;  // [64][72]
#pragma unroll
    for (int mf = 0; mf < 4; ++mf)
#pragma unroll
      for (int nf = 0; nf < 4; ++nf)
#pragma unroll
        for (int r = 0; r < 4; ++r)
          tp[(nf*16 + lr)*72 + mf*16 + g*4 + r] = f2bf(acc[mf][nf][r]);
    __syncthreads();
    const int nbase = m0 & (NN - 1);
    size_t vbase = ((size_t)(b*NHEAD + head)*HDIM)*NN;
#pragma unroll
    for (int it = 0; it < 8; ++it) {
      int j  = it*8 + (lane >> 3);
      int ns = (lane & 7)*8;
      s16x8 vv = *(const s16x8*)&tp[j*72 + ns];
      *(s16x8*)&vtb[vbase + (size_t)j*NN + nbase + ns] = vv;
    }
  }
}

// ---------------- fused flash attention ----------------
// Round-10 base (QBLK=128, 32 q/wave, 2 q-groups, XCD-pinned swizzle, permuted K staging,
// P in regs, ones-MFMA lsum, vcc-only defer-max) + 128-KEY STEPS: two independent 64-key
// half-bodies inside ONE barrier pair. Half-2's QK^T MFMAs overlap half-1's softmax VALU
// (T15 mechanism via unroll), and the barrier count halves (32 -> 16 per block).
// LDS 72KB/block -> still 2 blocks/CU.
__global__ __launch_bounds__(256) void attn_kernel(
    const short* __restrict__ qb, const short* __restrict__ kb,
    const short* __restrict__ vtb, const float* __restrict__ mbias,
    const int* __restrict__ mseg,
    short* __restrict__ attnb) {
  __shared__ short Kt[2][2][64*72];   // [buf][half][perm key][64 d + pad]
  __shared__ short Vt[2][2][64*72];   // [buf][half][64 d][64 keys + pad]
  const int tid = threadIdx.x, lane = tid & 63, wid = tid >> 6;
  const int g = lane >> 4, lr = lane & 15;
  const int w = blockIdx.x;
  const int bh = (w & 7)*4 + ((w >> 3) & 3);
  const int qt = w >> 5;
  const int b = bh >> 4;
  const int q0 = qt*128 + wid*32;

  const short* qpA = qb + ((size_t)bh*NN + q0 + lr)*HDIM + g*8;
  s16x8 qfA0 = *(const s16x8*)(qpA);
  s16x8 qfA1 = *(const s16x8*)(qpA + 32);
  const short* qpB = qpA + 16*HDIM;
  s16x8 qfB0 = *(const s16x8*)(qpB);
  s16x8 qfB1 = *(const s16x8*)(qpB + 32);

  s16x8 one8;
#pragma unroll
  for (int i = 0; i < 8; ++i) one8[i] = (short)0x3F80;  // bf16 1.0

  f32x4 accA[4], accB[4];
#pragma unroll
  for (int i = 0; i < 4; ++i) { accA[i] = zf4(); accB[i] = zf4(); }
  f32x4 acclA = zf4(), acclB = zf4();
  float mrunA = -3.0e38f, mrunB = -3.0e38f;

  const int* msp = mseg + b*(NN/64);
  int segflag = (lane < 32) ? msp[lane] : 0;
  unsigned segbits = (unsigned)__ballot(segflag != 0);

  const int sr = tid >> 2;
  const int sc = (tid & 3) * 16;
  const int rK = ((sr >> 5) & 1)*32 + ((sr >> 2) & 1)*16 + ((sr >> 3) & 3)*4 + (sr & 3);
  const short* kp = kb + (size_t)bh*NN*HDIM + (size_t)sr*HDIM + sc;
  const short* vp = vtb + ((size_t)bh*HDIM + sr)*NN + sc;
  const float* mb = mbias + b*NN;

  // prologue: stage tile 0 (128 keys)
  {
    s16x8 a0 = *(const s16x8*)(kp);
    s16x8 a1 = *(const s16x8*)(kp + 8);
    s16x8 a2 = *(const s16x8*)(kp + 64*HDIM);
    s16x8 a3 = *(const s16x8*)(kp + 64*HDIM + 8);
    s16x8 b0 = *(const s16x8*)(vp);
    s16x8 b1 = *(const s16x8*)(vp + 8);
    s16x8 b2 = *(const s16x8*)(vp + 64);
    s16x8 b3 = *(const s16x8*)(vp + 72);
    *(s16x8*)&Kt[0][0][rK*72 + sc]     = a0;
    *(s16x8*)&Kt[0][0][rK*72 + sc + 8] = a1;
    *(s16x8*)&Kt[0][1][rK*72 + sc]     = a2;
    *(s16x8*)&Kt[0][1][rK*72 + sc + 8] = a3;
    *(s16x8*)&Vt[0][0][sr*72 + sc]     = b0;
    *(s16x8*)&Vt[0][0][sr*72 + sc + 8] = b1;
    *(s16x8*)&Vt[0][1][sr*72 + sc]     = b2;
    *(s16x8*)&Vt[0][1][sr*72 + sc + 8] = b3;
  }
  __syncthreads();

  s16x8 kr0, kr1, kr2, kr3, vr0, vr1, vr2, vr3;
  int cur = 0;
  for (int k0 = 0; k0 < NN; k0 += 128) {
    const bool nl = (k0 + 128 < NN);
    if (nl) {  // issue next 128-key tile's global loads (L2-resident via XCD pinning)
      kp += 128*HDIM; vp += 128;
      kr0 = *(const s16x8*)(kp);
      kr1 = *(const s16x8*)(kp + 8);
      kr2 = *(const s16x8*)(kp + 64*HDIM);
      kr3 = *(const s16x8*)(kp + 64*HDIM + 8);
      vr0 = *(const s16x8*)(vp);
      vr1 = *(const s16x8*)(vp + 8);
      vr2 = *(const s16x8*)(vp + 64);
      vr3 = *(const s16x8*)(vp + 72);
    }

#pragma unroll
    for (int h = 0; h < 2; ++h) {
      const short* KtC = Kt[cur][h];
      const short* VtC = Vt[cur][h];
      const int kbase = k0 + h*64;

      f32x4 sA[4], sB[4];
      __builtin_amdgcn_s_setprio(1);
#pragma unroll
      for (int j = 0; j < 4; ++j) {
        s16x8 ka0 = *(const s16x8*)&KtC[(j*16 + lr)*72 + g*8];
        s16x8 ka1 = *(const s16x8*)&KtC[(j*16 + lr)*72 + 32 + g*8];
        sA[j] = mfma16(ka1, qfA1, mfma16(ka0, qfA0, zf4()));
        sB[j] = mfma16(ka1, qfB1, mfma16(ka0, qfB0, zf4()));
      }
      __builtin_amdgcn_s_setprio(0);

      if (segbits & (1u << (kbase >> 6))) {
#pragma unroll
        for (int j = 0; j < 4; ++j) {
          f32x4 bi = *(const f32x4*)&mb[kbase + (j >> 1)*32 + (j & 1)*4 + g*8];
#pragma unroll
          for (int r = 0; r < 4; ++r) { sA[j][r] += bi[r]; sB[j][r] += bi[r]; }
        }
      }

      float a0 = vmax3(sA[0][0], sA[0][1], sA[0][2]);
      float a1 = vmax3(sA[0][3], sA[1][0], sA[1][1]);
      float a2 = vmax3(sA[1][2], sA[1][3], sA[2][0]);
      float a3 = vmax3(sA[2][1], sA[2][2], sA[2][3]);
      float a4 = vmax3(sA[3][0], sA[3][1], sA[3][2]);
      float lmaxA = fmaxf(vmax3(a0, a1, a2), vmax3(a3, a4, sA[3][3]));
      float b0 = vmax3(sB[0][0], sB[0][1], sB[0][2]);
      float b1 = vmax3(sB[0][3], sB[1][0], sB[1][1]);
      float b2 = vmax3(sB[1][2], sB[1][3], sB[2][0]);
      float b3 = vmax3(sB[2][1], sB[2][2], sB[2][3]);
      float b4 = vmax3(sB[3][0], sB[3][1], sB[3][2]);
      float lmaxB = fmaxf(vmax3(b0, b1, b2), vmax3(b3, b4, sB[3][3]));

      if (__any(lmaxA > mrunA + 8.f)) {
        float rmax = fmaxf(lmaxA, __shfl_xor(lmaxA, 16));
        rmax = fmaxf(rmax, __shfl_xor(rmax, 32));
        float mnew = fmaxf(mrunA, rmax);
        float al = vexp2(mrunA - mnew);
        mrunA = mnew;
        float alr[4];
#pragma unroll
        for (int r = 0; r < 4; ++r)
          alr[r] = __shfl(al, (lane & 48) | (g*4 + r));
#pragma unroll
        for (int r = 0; r < 4; ++r) {
          accA[0][r] *= alr[r]; accA[1][r] *= alr[r];
          accA[2][r] *= alr[r]; accA[3][r] *= alr[r];
          acclA[r]   *= alr[r];
        }
      }
      if (__any(lmaxB > mrunB + 8.f)) {
        float rmax = fmaxf(lmaxB, __shfl_xor(lmaxB, 16));
        rmax = fmaxf(rmax, __shfl_xor(rmax, 32));
        float mnew = fmaxf(mrunB, rmax);
        float al = vexp2(mrunB - mnew);
        mrunB = mnew;
        float alr[4];
#pragma unroll
        for (int r = 0; r < 4; ++r)
          alr[r] = __shfl(al, (lane & 48) | (g*4 + r));
#pragma unroll
        for (int r = 0; r < 4; ++r) {
          accB[0][r] *= alr[r]; accB[1][r] *= alr[r];
          accB[2][r] *= alr[r]; accB[3][r] *= alr[r];
          acclB[r]   *= alr[r];
        }
      }

      union { unsigned u[4]; s16x8 v; } A0, A1, B0, B1;
      {
        float p[4][4];
#pragma unroll
        for (int j = 0; j < 4; ++j) {
          p[j][0] = vexp2(sA[j][0] - mrunA);
          p[j][1] = vexp2(sA[j][1] - mrunA);
          p[j][2] = vexp2(sA[j][2] - mrunA);
          p[j][3] = vexp2(sA[j][3] - mrunA);
        }
        A0.u[0] = cvtpk_bf16(p[0][0], p[0][1]);
        A0.u[1] = cvtpk_bf16(p[0][2], p[0][3]);
        A0.u[2] = cvtpk_bf16(p[1][0], p[1][1]);
        A0.u[3] = cvtpk_bf16(p[1][2], p[1][3]);
        A1.u[0] = cvtpk_bf16(p[2][0], p[2][1]);
        A1.u[1] = cvtpk_bf16(p[2][2], p[2][3]);
        A1.u[2] = cvtpk_bf16(p[3][0], p[3][1]);
        A1.u[3] = cvtpk_bf16(p[3][2], p[3][3]);
      }
      {
        float p[4][4];
#pragma unroll
        for (int j = 0; j < 4; ++j) {
          p[j][0] = vexp2(sB[j][0] - mrunB);
          p[j][1] = vexp2(sB[j][1] - mrunB);
          p[j][2] = vexp2(sB[j][2] - mrunB);
          p[j][3] = vexp2(sB[j][3] - mrunB);
        }
        B0.u[0] = cvtpk_bf16(p[0][0], p[0][1]);
        B0.u[1] = cvtpk_bf16(p[0][2], p[0][3]);
        B0.u[2] = cvtpk_bf16(p[1][0], p[1][1]);
        B0.u[3] = cvtpk_bf16(p[1][2], p[1][3]);
        B1.u[0] = cvtpk_bf16(p[2][0], p[2][1]);
        B1.u[1] = cvtpk_bf16(p[2][2], p[2][3]);
        B1.u[2] = cvtpk_bf16(p[3][0], p[3][1]);
        B1.u[3] = cvtpk_bf16(p[3][2], p[3][3]);
      }

      // early staging writes (last half only): target buf^1, hide under final PV
      if (h == 1 && nl) {
        *(s16x8*)&Kt[cur^1][0][rK*72 + sc]     = kr0;
        *(s16x8*)&Kt[cur^1][0][rK*72 + sc + 8] = kr1;
        *(s16x8*)&Kt[cur^1][1][rK*72 + sc]     = kr2;
        *(s16x8*)&Kt[cur^1][1][rK*72 + sc + 8] = kr3;
        *(s16x8*)&Vt[cur^1][0][sr*72 + sc]     = vr0;
        *(s16x8*)&Vt[cur^1][0][sr*72 + sc + 8] = vr1;
        *(s16x8*)&Vt[cur^1][1][sr*72 + sc]     = vr2;
        *(s16x8*)&Vt[cur^1][1][sr*72 + sc + 8] = vr3;
      }

      __builtin_amdgcn_s_setprio(1);
      acclA = mfma16(A0.v, one8, acclA);
      acclA = mfma16(A1.v, one8, acclA);
      acclB = mfma16(B0.v, one8, acclB);
      acclB = mfma16(B1.v, one8, acclB);
#pragma unroll
      for (int db = 0; db < 4; ++db) {
        s16x8 vb0 = *(const s16x8*)&VtC[(db*16 + lr)*72 + g*8];
        s16x8 vb1 = *(const s16x8*)&VtC[(db*16 + lr)*72 + 32 + g*8];
        accA[db] = mfma16(A0.v, vb0, accA[db]);
        accA[db] = mfma16(A1.v, vb1, accA[db]);
        accB[db] = mfma16(B0.v, vb0, accB[db]);
        accB[db] = mfma16(B1.v, vb1, accB[db]);
      }
      __builtin_amdgcn_s_setprio(0);
    }

    if (nl) {
      __syncthreads();
      cur ^= 1;
    }
  }

#pragma unroll
  for (int r = 0; r < 4; ++r) {
    float invA = vrcp(acclA[r]);
    float invB = vrcp(acclB[r]);
    size_t rowA = (size_t)(b*NN + q0 + g*4 + r);
    size_t rowB = rowA + 16;
#pragma unroll
    for (int db = 0; db < 4; ++db) {
      attnb[rowA*HH + (bh & 15)*64 + db*16 + lr] = f2bf(accA[db][r]*invA);
      attnb[rowB*HH + (bh & 15)*64 + db*16 + lr] = f2bf(accB[db][r]*invB);
    }
  }
}

// ---------------- output projection (fp32 out) ----------------
__global__ __launch_bounds__(256) void outproj_kernel(
    const short* __restrict__ attnb, const short* __restrict__ wob,
    float* __restrict__ out) {
  __shared__ short smem[16384];
  const int bm = blockIdx.y, bn = blockIdx.x;
  f32x4 acc[4][4];
  gemm128_core(attnb, wob, bm, bn, smem, acc);
  const int tid = threadIdx.x, lane = tid & 63, wid = tid >> 6;
  const int wr = wid >> 1, wc = wid & 1, g = lane >> 4, lr = lane & 15;
  const int m0 = bm*128 + wr*64;
  const int c0 = bn*128 + wc*64;
#pragma unroll
  for (int mf = 0; mf < 4; ++mf)
#pragma unroll
    for (int r = 0; r < 4; ++r) {
      int m = m0 + mf*16 + g*4 + r;
      float* po = out + (size_t)m*HH + c0;
#pragma unroll
      for (int nf = 0; nf < 4; ++nf)
        po[nf*16 + lr] = acc[mf][nf][r];
    }
}

extern "C" void kernel_launch(void* const* d_in, const int* in_sizes, int n_in,
                              void* d_out, int out_size, void* d_ws, size_t ws_size,
                              hipStream_t stream) {
  const float* feat = (const float*)d_in[0];
  const int*   mask = (const int*)d_in[1];
  const float* wq   = (const float*)d_in[2];
  const float* wk   = (const float*)d_in[3];
  const float* wv   = (const float*)d_in[4];
  const float* wo   = (const float*)d_in[5];
  float* out = (float*)d_out;

  char* ws = (char*)d_ws;
  size_t off = 0;
  short* fbf = (short*)(ws + off); off += (size_t)BB*NN*HH*2;
  short* wqb = (short*)(ws + off); off += (size_t)HH*HH*2;
  short* wkb = (short*)(ws + off); off += (size_t)HH*HH*2;
  short* wvb = (short*)(ws + off); off += (size_t)HH*HH*2;
  short* wob = (short*)(ws + off); off += (size_t)HH*HH*2;
  float* cosb = (float*)(ws + off); off += (size_t)NN*32*4;
  float* sinb = (float*)(ws + off); off += (size_t)NN*32*4;
  float* mbias = (float*)(ws + off); off += (size_t)BB*NN*4;
  int* msegb = (int*)(ws + off); off += (size_t)BB*(NN/64)*4;
  short* qbuf = (short*)(ws + off); off += (size_t)BB*NN*HH*2;
  short* kbuf = (short*)(ws + off); off += (size_t)BB*NN*HH*2;
  short* vtbuf = (short*)(ws + off); off += (size_t)BB*NN*HH*2;
  short* attnb = (short*)(ws + off); off += (size_t)BB*NN*HH*2;

  prep_kernel<<<1024, 256, 0, stream>>>(feat, mask, wq, wk, wv, wo,
                                        fbf, wqb, wkb, wvb, wob, cosb, sinb,
                                        mbias, msegb);
  qkv_kernel<<<dim3(HH/128, BB*NN/128, 3), 256, 0, stream>>>(
      fbf, wqb, wkb, wvb, cosb, sinb, qbuf, kbuf, vtbuf);
  attn_kernel<<<512, 256, 0, stream>>>(
      qbuf, kbuf, vtbuf, mbias, msegb, attnb);
  outproj_kernel<<<dim3(HH/128, BB*NN/128), 256, 0, stream>>>(attnb, wob, out);
}